// Round 13
// baseline (1021.372 us; speedup 1.0000x reference)
//
#include <hip/hip_runtime.h>
#include <hip/hip_bf16.h>

// ---------------------------------------------------------------------------
// VGG16 perceptual+style inpainting loss.
// conv1: bf16 MFMA im2col-K32 -> fp8 (channel-permuted) output.
// conv2..7: fp8(e4m3) MFMA NHWC using 32x32x16 MFMA (2x FLOP per LDS byte vs
// 16x16x32). Activations stored with 64-ch groups permuted pos=kh*32+kc*8+j
// (kh=(c>>3)&1, kc=c>>4, j=c&7) so one ds_read_b128 feeds two K=16 chunks.
// 4-way XOR chunk swizzle on LDS addresses breaks 64B-stride bank clustering.
// A-frags cached across dy. Pool epilogues dual-store fp8(perm)+bf16(logical).
// Gram: bf16 MFMA planar. Workspace layout identical to r11/r12.
// ---------------------------------------------------------------------------

typedef __attribute__((ext_vector_type(8))) short bf16x8_t;
typedef __attribute__((ext_vector_type(4))) float f32x4_t;
typedef __attribute__((ext_vector_type(16))) float f32x16_t;

__device__ __forceinline__ float b2f(__hip_bfloat16 v) {
  return __bfloat162float(v);
}

__device__ __forceinline__ unsigned char f2fp8(float v) {
  return (unsigned char)(__builtin_amdgcn_cvt_pk_fp8_f32(v, v, 0, false) & 0xff);
}

// channel -> stored position within a 64-group (K=16-chunk pairing layout)
__device__ __forceinline__ int p64(int c) {
  return ((c >> 3) & 1) * 32 + ((c >> 4) & 3) * 8 + (c & 7);
}

__device__ __forceinline__ float blk_sum256(float v, float* s4) {
#pragma unroll
  for (int o = 32; o > 0; o >>= 1) v += __shfl_down(v, o);
  int w = threadIdx.x >> 6;
  if ((threadIdx.x & 63) == 0) s4[w] = v;
  __syncthreads();
  float r = s4[0] + s4[1] + s4[2] + s4[3];
  __syncthreads();
  return r;
}

__global__ void init_slots(float* slots) {
  if (threadIdx.x < 8) slots[threadIdx.x] = 0.0f;
}

__global__ __launch_bounds__(256) void l1_kernel(
    const float* __restrict__ igt, const float* __restrict__ iout,
    const float* __restrict__ mask, float* __restrict__ slots) {
  __shared__ float s4[4];
  float ah = 0.0f, av = 0.0f;
  for (int idx = blockIdx.x * 256 + threadIdx.x; idx < 1572864;
       idx += gridDim.x * 256) {
    int pix = idx & 262143;
    int n = idx / 786432;
    float mk = mask[n * 262144 + pix];
    bool m = (mk != 0.0f);
    float d = fabsf(iout[idx] - igt[idx]);
    if (m) av += d; else ah += d;
  }
  float r = blk_sum256(ah, s4);
  if (threadIdx.x == 0) atomicAdd(&slots[0], r);
  r = blk_sum256(av, s4);
  if (threadIdx.x == 0) atomicAdd(&slots[1], r);
}

// Pack fp32 OIHW weights -> fp8 [tap][cout][cin-permuted] (conv2..7).
__global__ __launch_bounds__(256) void pack_w(const float* __restrict__ w,
                                              unsigned char* __restrict__ wp,
                                              int Cin, int Cout) {
  int i = blockIdx.x * 256 + threadIdx.x;
  if (i >= Cout * Cin * 9) return;
  int o = i % 9;
  int rem = i / 9;
  int ci = rem % Cin;
  int co = rem / Cin;
  int cis = (ci & ~63) + p64(ci & 63);
  wp[((long)(o * Cout + co)) * Cin + cis] = f2fp8(w[i]);
}

// Pack conv1 weights [64][3][3][3] OIHW -> bf16 [co][32], k=dy*9+dx*3+ci.
__global__ __launch_bounds__(256) void pack_w1(const float* __restrict__ w,
                                               __hip_bfloat16* __restrict__ wk) {
  int i = blockIdx.x * 256 + threadIdx.x;
  if (i >= 64 * 32) return;
  int co = i >> 5, k = i & 31;
  float v = 0.0f;
  if (k < 27) {
    int dy = k / 9, r = k - dy * 9;
    int dx = r / 3, ci = r - dx * 3;
    v = w[((co * 3 + ci) * 3 + dy) * 3 + dx];
  }
  wk[i] = __float2bfloat16(v);
}

// Build im2col-K32 bf16 input Apk[nl][y][x][32] for stream sid. (r10-proven)
__global__ __launch_bounds__(256) void pack2_kernel(
    const float* __restrict__ igt, const float* __restrict__ iout,
    const float* __restrict__ mask, __hip_bfloat16* __restrict__ apk, int sid,
    int n0, int NB) {
  int idx = blockIdx.x * 256 + threadIdx.x;
  if (idx >= NB * 262144) return;
  int nl = idx >> 18;
  int pix = idx & 262143;
  int y = pix >> 9, x = pix & 511;
  int sample = n0 + nl;
  __align__(16) __hip_bfloat16 buf[32];
#pragma unroll
  for (int k = 27; k < 32; ++k) buf[k] = __float2bfloat16(0.0f);
  for (int dy = 0; dy < 3; ++dy)
    for (int dx = 0; dx < 3; ++dx) {
      int gy = y - 1 + dy, gx = x - 1 + dx;
      bool inb = (gy >= 0 && gy < 512 && gx >= 0 && gx < 512);
      int p = gy * 512 + gx;
      bool useG;
      if (sid == 0) useG = true;
      else if (sid == 1) useG = false;
      else useG = inb && (mask[sample * 262144 + (inb ? p : 0)] != 0.0f);
      const float* src = useG ? igt : iout;
#pragma unroll
      for (int ci = 0; ci < 3; ++ci) {
        float v = inb ? src[sample * 786432 + ci * 262144 + p] : 0.0f;
        buf[dy * 9 + dx * 3 + ci] = __float2bfloat16(v);
      }
    }
  __hip_bfloat16* dst = apk + (long)idx * 32;
#pragma unroll
  for (int q = 0; q < 4; ++q)
    *(uint4*)&dst[q * 8] = *(const uint4*)&buf[q * 8];
}

// conv1: K=32 bf16 MFMA GEMM -> fp8 NHWC Y1 (permuted channel positions).
__global__ __launch_bounds__(256, 2) void conv1m(
    const __hip_bfloat16* __restrict__ apk, const __hip_bfloat16* __restrict__ wk,
    const float* __restrict__ bias, unsigned char* __restrict__ out) {
  __shared__ __align__(16) short ApS[512 * 32];
  __shared__ __align__(16) short BwS[64 * 32];
  const int tid = threadIdx.x;
  const int lane = tid & 63;
  const int wv = tid >> 6;
  const int quad = lane >> 4, l15 = lane & 15;
  const int n = blockIdx.z;
  const int x0 = blockIdx.x << 6;
  const int y0 = blockIdx.y << 3;

  for (int e = tid; e < 2048; e += 256) {
    int q = e & 3, pos = e >> 2;
    int r = pos >> 6, c = pos & 63;
    *(uint4*)&ApS[pos * 32 + q * 8] =
        *(const uint4*)(apk + (((long)n * 512 + y0 + r) * 512 + x0 + c) * 32 +
                        q * 8);
  }
  if (tid < 256) {
    int q = tid & 3, co = tid >> 2;
    *(uint4*)&BwS[co * 32 + q * 8] = *(const uint4*)(wk + co * 32 + q * 8);
  }
  __syncthreads();

  f32x4_t acc[8][4];
#pragma unroll
  for (int mt = 0; mt < 8; ++mt)
#pragma unroll
    for (int nt = 0; nt < 4; ++nt) acc[mt][nt] = (f32x4_t)0.0f;

  bf16x8_t bf[4];
#pragma unroll
  for (int nt = 0; nt < 4; ++nt)
    bf[nt] = *(const bf16x8_t*)&BwS[(nt * 16 + l15) * 32 + quad * 8];
#pragma unroll
  for (int mt = 0; mt < 8; ++mt) {
    const int rl = 2 * wv + (mt >> 2);
    const int pl = (mt & 3) * 16 + l15;
    const bf16x8_t a = *(const bf16x8_t*)&ApS[(rl * 64 + pl) * 32 + quad * 8];
#pragma unroll
    for (int nt = 0; nt < 4; ++nt)
      acc[mt][nt] = __builtin_amdgcn_mfma_f32_16x16x32_bf16(a, bf[nt],
                                                            acc[mt][nt], 0, 0, 0);
  }

  float bv[4];
#pragma unroll
  for (int nt = 0; nt < 4; ++nt) bv[nt] = bias[nt * 16 + l15];
#pragma unroll
  for (int mt = 0; mt < 8; ++mt) {
    const int y = y0 + 2 * wv + (mt >> 2);
#pragma unroll
    for (int nt = 0; nt < 4; ++nt) {
      const int colp = p64(nt * 16 + l15);
#pragma unroll
      for (int reg = 0; reg < 4; ++reg) {
        int px = (mt & 3) * 16 + quad * 4 + reg;
        float v = fmaxf(acc[mt][nt][reg] + bv[nt], 0.0f);
        out[(((long)n * 512 + y) * 512 + x0 + px) * 64 + colp] = f2fp8(v);
      }
    }
  }
}

// ---------------------------------------------------------------------------
// conv_f8 v3: fp8 MFMA 3x3 conv using 32x32x16 MFMA. Wave = 2 rows x 64 px
// x 64 co = 4 m-tiles(32px) x 2 n-tiles(32co); acc 8x16 f32. One b128 feeds
// two K=16 chunks (kh=lane>>5 half). A-frags cached across dy. XOR-4 chunk
// swizzle on LDS addresses. LDS: A 42,240B + W 36,864B -> 2 blk/CU.
// Block = 4 waves = 8 rows x 64 px x 64 co (grids identical to r12).
// ---------------------------------------------------------------------------
__global__ __launch_bounds__(256, 2) void conv_f8(
    const unsigned char* __restrict__ act, const unsigned char* __restrict__ wp,
    const float* __restrict__ bias, unsigned char* __restrict__ out, int Cin,
    int Cout, int H, int W) {
  __shared__ __align__(16) unsigned char ApS[660 * 64];
  __shared__ __align__(16) unsigned char BwS[576 * 64];
  const int tid = threadIdx.x;
  const int lane = tid & 63;
  const int wv = tid >> 6;
  const int l31 = lane & 31;
  const int kh = lane >> 5;
  const int coB = Cout >> 6;
  const int n = blockIdx.z / coB;
  const int co0 = (blockIdx.z % coB) << 6;
  const int x0 = blockIdx.x << 6;
  const int y0 = blockIdx.y << 3;

  f32x16_t acc[4][2];
#pragma unroll
  for (int mt = 0; mt < 4; ++mt)
#pragma unroll
    for (int nt = 0; nt < 2; ++nt) acc[mt][nt] = (f32x16_t)0.0f;

  for (int cb = 0; cb < Cin; cb += 64) {
    for (int e = tid; e < 2640; e += 256) {  // A: 660 px * 4 x 16B
      int q = e & 3, pos = e >> 2;
      int r = pos / 66, c = pos - r * 66;
      int gy = y0 - 1 + r, gx = x0 - 1 + c;
      uint4 v = make_uint4(0, 0, 0, 0);
      if (gy >= 0 && gy < H && gx >= 0 && gx < W)
        v = *(const uint4*)(act + ((long)((long)n * H + gy) * W + gx) * Cin +
                            cb + q * 16);
      *(uint4*)&ApS[pos * 64 + ((q * 16) ^ ((pos & 3) * 16))] = v;
    }
    for (int e = tid; e < 2304; e += 256) {  // W: 576 rows * 4 x 16B
      int q = e & 3, idx = e >> 2;
      int o = idx >> 6, co = idx & 63;
      *(uint4*)&BwS[idx * 64 + ((q * 16) ^ ((idx & 3) * 16))] =
          *(const uint4*)(wp + ((long)(o * Cout + co0 + co)) * Cin + cb +
                          q * 16);
    }
    __syncthreads();

#pragma unroll
    for (int dx = 0; dx < 3; ++dx) {
      long long Af[4][2][4];  // [row-variant t][px-tile][kchunk]
#pragma unroll
      for (int t = 0; t < 4; ++t)
#pragma unroll
        for (int pxt = 0; pxt < 2; ++pxt) {
          const int pos = (2 * wv + t) * 66 + pxt * 32 + l31 + dx;
#pragma unroll
          for (int p = 0; p < 2; ++p) {
            uint4 a4 = *(const uint4*)&ApS
                [pos * 64 + (((kh * 2 + p) * 16) ^ ((pos & 3) * 16))];
            Af[t][pxt][2 * p] = ((long long)a4.y << 32) | a4.x;
            Af[t][pxt][2 * p + 1] = ((long long)a4.w << 32) | a4.z;
          }
        }
#pragma unroll
      for (int dy = 0; dy < 3; ++dy) {
        const int o = dy * 3 + dx;
        long long Bf[2][4];
#pragma unroll
        for (int nt = 0; nt < 2; ++nt) {
          const int idx = (o << 6) + nt * 32 + l31;
#pragma unroll
          for (int p = 0; p < 2; ++p) {
            uint4 b4 = *(const uint4*)&BwS
                [idx * 64 + (((kh * 2 + p) * 16) ^ ((idx & 3) * 16))];
            Bf[nt][2 * p] = ((long long)b4.y << 32) | b4.x;
            Bf[nt][2 * p + 1] = ((long long)b4.w << 32) | b4.z;
          }
        }
#pragma unroll
        for (int kc = 0; kc < 4; ++kc)
#pragma unroll
          for (int mt = 0; mt < 4; ++mt) {
            const int t = (mt >> 1) + dy;
            const int pxt = mt & 1;
#pragma unroll
            for (int nt = 0; nt < 2; ++nt)
              acc[mt][nt] = __builtin_amdgcn_mfma_f32_32x32x16_fp8_fp8(
                  Af[t][pxt][kc], Bf[nt][kc], acc[mt][nt], 0, 0, 0);
          }
      }
    }
    __syncthreads();
  }

  float bv[2];
#pragma unroll
  for (int nt = 0; nt < 2; ++nt) bv[nt] = bias[co0 + nt * 32 + l31];
#pragma unroll
  for (int mt = 0; mt < 4; ++mt) {
    const int y = y0 + 2 * wv + (mt >> 1);
    const int pxb = x0 + (mt & 1) * 32;
#pragma unroll
    for (int nt = 0; nt < 2; ++nt) {
      const int colp = co0 + p64(nt * 32 + l31);
#pragma unroll
      for (int reg = 0; reg < 16; ++reg) {
        int px = pxb + (reg & 3) + 8 * (reg >> 2) + 4 * kh;
        float v = fmaxf(acc[mt][nt][reg] + bv[nt], 0.0f);
        out[(((long)n * H + y) * W + px) * Cout + colp] = f2fp8(v);
      }
    }
  }
}

// conv_f8p v3: conv_f8 + fused 2x2 maxpool; dual-store fp8(perm)+bf16(logical).
// x-pairs = acc reg pairs (2rq,2rq+1); row pair = acc[mt] vs acc[mt+2].
__global__ __launch_bounds__(256, 2) void conv_f8p(
    const unsigned char* __restrict__ act, const unsigned char* __restrict__ wp,
    const float* __restrict__ bias, unsigned char* __restrict__ outF,
    __hip_bfloat16* __restrict__ outB, int Cin, int Cout, int H, int W) {
  __shared__ __align__(16) unsigned char ApS[660 * 64];
  __shared__ __align__(16) unsigned char BwS[576 * 64];
  const int tid = threadIdx.x;
  const int lane = tid & 63;
  const int wv = tid >> 6;
  const int l31 = lane & 31;
  const int kh = lane >> 5;
  const int coB = Cout >> 6;
  const int n = blockIdx.z / coB;
  const int co0 = (blockIdx.z % coB) << 6;
  const int x0g = blockIdx.x << 6;
  const int y0 = blockIdx.y << 3;

  f32x16_t acc[4][2];
#pragma unroll
  for (int mt = 0; mt < 4; ++mt)
#pragma unroll
    for (int nt = 0; nt < 2; ++nt) acc[mt][nt] = (f32x16_t)0.0f;

  for (int cb = 0; cb < Cin; cb += 64) {
    for (int e = tid; e < 2640; e += 256) {
      int q = e & 3, pos = e >> 2;
      int r = pos / 66, c = pos - r * 66;
      int gy = y0 - 1 + r, gx = x0g - 1 + c;
      uint4 v = make_uint4(0, 0, 0, 0);
      if (gy >= 0 && gy < H && gx >= 0 && gx < W)
        v = *(const uint4*)(act + ((long)((long)n * H + gy) * W + gx) * Cin +
                            cb + q * 16);
      *(uint4*)&ApS[pos * 64 + ((q * 16) ^ ((pos & 3) * 16))] = v;
    }
    for (int e = tid; e < 2304; e += 256) {
      int q = e & 3, idx = e >> 2;
      int o = idx >> 6, co = idx & 63;
      *(uint4*)&BwS[idx * 64 + ((q * 16) ^ ((idx & 3) * 16))] =
          *(const uint4*)(wp + ((long)(o * Cout + co0 + co)) * Cin + cb +
                          q * 16);
    }
    __syncthreads();

#pragma unroll
    for (int dx = 0; dx < 3; ++dx) {
      long long Af[4][2][4];
#pragma unroll
      for (int t = 0; t < 4; ++t)
#pragma unroll
        for (int pxt = 0; pxt < 2; ++pxt) {
          const int pos = (2 * wv + t) * 66 + pxt * 32 + l31 + dx;
#pragma unroll
          for (int p = 0; p < 2; ++p) {
            uint4 a4 = *(const uint4*)&ApS
                [pos * 64 + (((kh * 2 + p) * 16) ^ ((pos & 3) * 16))];
            Af[t][pxt][2 * p] = ((long long)a4.y << 32) | a4.x;
            Af[t][pxt][2 * p + 1] = ((long long)a4.w << 32) | a4.z;
          }
        }
#pragma unroll
      for (int dy = 0; dy < 3; ++dy) {
        const int o = dy * 3 + dx;
        long long Bf[2][4];
#pragma unroll
        for (int nt = 0; nt < 2; ++nt) {
          const int idx = (o << 6) + nt * 32 + l31;
#pragma unroll
          for (int p = 0; p < 2; ++p) {
            uint4 b4 = *(const uint4*)&BwS
                [idx * 64 + (((kh * 2 + p) * 16) ^ ((idx & 3) * 16))];
            Bf[nt][2 * p] = ((long long)b4.y << 32) | b4.x;
            Bf[nt][2 * p + 1] = ((long long)b4.w << 32) | b4.z;
          }
        }
#pragma unroll
        for (int kc = 0; kc < 4; ++kc)
#pragma unroll
          for (int mt = 0; mt < 4; ++mt) {
            const int t = (mt >> 1) + dy;
            const int pxt = mt & 1;
#pragma unroll
            for (int nt = 0; nt < 2; ++nt)
              acc[mt][nt] = __builtin_amdgcn_mfma_f32_32x32x16_fp8_fp8(
                  Af[t][pxt][kc], Bf[nt][kc], acc[mt][nt], 0, 0, 0);
          }
      }
    }
    __syncthreads();
  }

  const int Ho = H >> 1, Wo = W >> 1;
  const int ho = (y0 >> 1) + wv;
  float bv[2];
#pragma unroll
  for (int nt = 0; nt < 2; ++nt) bv[nt] = bias[co0 + nt * 32 + l31];
#pragma unroll
  for (int mtA = 0; mtA < 2; ++mtA) {  // px-tile
#pragma unroll
    for (int nt = 0; nt < 2; ++nt) {
      const int col = co0 + nt * 32 + l31;
      const int colp = co0 + p64(nt * 32 + l31);
#pragma unroll
      for (int rq = 0; rq < 8; ++rq) {
        float m0 = fmaxf(
            fmaxf(acc[mtA][nt][2 * rq], acc[mtA][nt][2 * rq + 1]),
            fmaxf(acc[mtA + 2][nt][2 * rq], acc[mtA + 2][nt][2 * rq + 1]));
        float v = fmaxf(m0 + bv[nt], 0.0f);
        int wo = (x0g >> 1) + mtA * 16 + (rq & 1) + 4 * (rq >> 1) + 2 * kh;
        long rowbase = (((long)n * Ho + ho) * Wo + wo) * Cout;
        outF[rowbase + colp] = f2fp8(v);
        outB[rowbase + col] = __float2bfloat16(v);
      }
    }
  }
}

// NHWC [j][Ho][Wo][C] -> col-major planar [(j*C+c)][Wo][Ho]. (r10-proven)
__global__ __launch_bounds__(256) void transpose_k(
    const __hip_bfloat16* __restrict__ in, __hip_bfloat16* __restrict__ out,
    int C, int Ho, int Wo) {
  const int cl = threadIdx.x & 31;
  const int wl = threadIdx.x >> 5;
  const int cg = C >> 5;
  const int j = blockIdx.z / cg;
  const int c = (blockIdx.z % cg) * 32 + cl;
  const int wo = blockIdx.x * 8 + wl;
  const int ho0 = blockIdx.y * 8;
  __align__(16) __hip_bfloat16 res[8];
#pragma unroll
  for (int i = 0; i < 8; ++i)
    res[i] = in[(((long)j * Ho + ho0 + i) * Wo + wo) * C + c];
  *(uint4*)&out[((long)(j * C + c) * Wo + wo) * Ho + ho0] =
      *(const uint4*)res;
}

// l_perc partial: sum |cur - gt| over 8*M8 bf16 elements -> slots[2]
__global__ __launch_bounds__(256) void perc_kernel(
    const __hip_bfloat16* __restrict__ gt, const __hip_bfloat16* __restrict__ cur,
    int M8, float* __restrict__ slots) {
  __shared__ float s4[4];
  const uint4* g4 = (const uint4*)gt;
  const uint4* c4 = (const uint4*)cur;
  float acc = 0.0f;
  for (int i = blockIdx.x * 256 + threadIdx.x; i < M8; i += gridDim.x * 256) {
    uint4 g = g4[i], c = c4[i];
    const unsigned* gu = (const unsigned*)&g;
    const unsigned* cu = (const unsigned*)&c;
#pragma unroll
    for (int k = 0; k < 4; ++k) {
      float g0 = __uint_as_float(gu[k] << 16);
      float g1 = __uint_as_float(gu[k] & 0xffff0000u);
      float c0 = __uint_as_float(cu[k] << 16);
      float c1 = __uint_as_float(cu[k] & 0xffff0000u);
      acc += fabsf(c0 - g0) + fabsf(c1 - g1);
    }
  }
  float r = blk_sum256(acc, s4);
  if (threadIdx.x == 0) atomicAdd(&slots[2], r);
}

// Style partial via bf16 MFMA (r5-proven). Inputs col-major planar bf16.
template <int BM>
__global__ __launch_bounds__(256) void gram_mfma(
    const __hip_bfloat16* __restrict__ gt_p,
    const __hip_bfloat16* __restrict__ cur_p, int Wp, int Hp, float fscale,
    float* __restrict__ slots) {
  constexpr int COLS = BM + 64;
  constexpr int WR = BM / 4;
  constexpr int MT = WR / 16;
  __shared__ __align__(16) short S[2 * COLS * 40];
  __shared__ float s4[4];
  const int tid = threadIdx.x;
  const int lane = tid & 63;
  const int wvi = tid >> 6;
  const int quad = lane >> 4, l15 = lane & 15;
  const int vt = blockIdx.x * 64;
  const int wt = blockIdx.y * BM;
  const long plane = (long)blockIdx.z * Wp * Hp;
  const __hip_bfloat16* bases[2] = {gt_p + plane, cur_p + plane};

  f32x4_t acc[2][MT][4];
#pragma unroll
  for (int t = 0; t < 2; ++t)
#pragma unroll
    for (int mt = 0; mt < MT; ++mt)
#pragma unroll
      for (int nt = 0; nt < 4; ++nt) acc[t][mt][nt] = (f32x4_t)0.0f;

  const int nchunk = 2 * COLS * 4;
  for (int h0 = 0; h0 < Hp; h0 += 32) {
    for (int e = tid; e < nchunk; e += 256) {
      int chunk = e & 3;
      int colt = e >> 2;
      int t = colt / COLS;
      int col = colt - t * COLS;
      int sc = (col < BM) ? (wt + col) : (vt + col - BM);
      uint4 v = *(const uint4*)(bases[t] + (long)sc * Hp + h0 + chunk * 8);
      *(uint4*)&S[(t * COLS + col) * 40 + chunk * 8] = v;
    }
    __syncthreads();
#pragma unroll
    for (int t = 0; t < 2; ++t) {
      bf16x8_t bf[4];
#pragma unroll
      for (int nt = 0; nt < 4; ++nt)
        bf[nt] = *(const bf16x8_t*)&S[(t * COLS + BM + nt * 16 + l15) * 40 +
                                      quad * 8];
#pragma unroll
      for (int mt = 0; mt < MT; ++mt) {
        bf16x8_t a = *(const bf16x8_t*)&S[(t * COLS + wvi * WR + mt * 16 + l15) *
                                              40 + quad * 8];
#pragma unroll
        for (int nt = 0; nt < 4; ++nt)
          acc[t][mt][nt] = __builtin_amdgcn_mfma_f32_16x16x32_bf16(
              a, bf[nt], acc[t][mt][nt], 0, 0, 0);
      }
    }
    __syncthreads();
  }

  float local = 0.0f;
#pragma unroll
  for (int mt = 0; mt < MT; ++mt)
#pragma unroll
    for (int nt = 0; nt < 4; ++nt)
#pragma unroll
      for (int reg = 0; reg < 4; ++reg)
        local += fabsf(acc[1][mt][nt][reg] - acc[0][mt][nt][reg]);
  float r = blk_sum256(local, s4);
  if (tid == 0) atomicAdd(&slots[3], r * fscale);
}

__global__ void combine_kernel(const float* __restrict__ slots,
                               float* __restrict__ out) {
  if (threadIdx.x == 0) {
    const float Nn = 1572864.0f;
    const float Nigt = 8388608.0f;
    out[0] = 2.0f * slots[0] / Nn + slots[1] / Nn + slots[2] / Nigt + slots[3];
  }
}

extern "C" void kernel_launch(void* const* d_in, const int* in_sizes, int n_in,
                              void* d_out, int out_size, void* d_ws,
                              size_t ws_size, hipStream_t stream) {
  (void)in_sizes; (void)n_in; (void)out_size;
  const float* igt = (const float*)d_in[0];
  const float* iout = (const float*)d_in[1];
  const float* mask = (const float*)d_in[2];
  const float* w[7];
  const float* b[7];
  for (int i = 0; i < 7; ++i) {
    w[i] = (const float*)d_in[3 + 2 * i];
    b[i] = (const float*)d_in[4 + 2 * i];
  }
  float* slots = (float*)d_ws;

  unsigned char* wpk = (unsigned char*)((char*)d_ws + 256);
  const long wpOff[6] = {0, 36864, 110592, 258048, 552960, 1142784};
  const int wpCin[6] = {64, 64, 128, 128, 256, 256};
  const int wpCout[6] = {64, 128, 128, 256, 256, 256};
  __hip_bfloat16* w1k = (__hip_bfloat16*)((char*)d_ws + 256 + 1732608);
  // weights end at byte 1,736,960

  const size_t NEED2 = 194674944ULL;
  const int NB = (ws_size >= NEED2) ? 2 : 1;
  const int B3 = 3 * NB;

  char* base = (char*)d_ws + 1736960;
  __hip_bfloat16* Apk = (__hip_bfloat16*)base;
  unsigned char* Y1 = (unsigned char*)(base + (size_t)NB * 16777216);
  unsigned char* P1N8 = (unsigned char*)(base + (size_t)NB * 33554432);
  __hip_bfloat16* P1Nb = (__hip_bfloat16*)(base + (size_t)NB * 46137344);
  __hip_bfloat16* pgT1 = (__hip_bfloat16*)(base + (size_t)NB * 54525952);
  __hip_bfloat16* pcT1 = (__hip_bfloat16*)(base + (size_t)NB * 62914560);
  __hip_bfloat16* P2Nb = (__hip_bfloat16*)(base + (size_t)NB * 71303168);
  __hip_bfloat16* P2T = (__hip_bfloat16*)(base + (size_t)NB * 83886080);
  unsigned char* T = (unsigned char*)base;
  unsigned char* P2N8 = (unsigned char*)(base + (size_t)NB * 46137344);
  unsigned char* Y5 = (unsigned char*)base;
  unsigned char* Y6 = (unsigned char*)(base + (size_t)NB * 12582912);
  __hip_bfloat16* P3Nb = (__hip_bfloat16*)(base + (size_t)NB * 33554432);
  __hip_bfloat16* P3T = (__hip_bfloat16*)(base + (size_t)NB * 39845888);
  unsigned char* P3N8 = (unsigned char*)(base + (size_t)NB * 46137344);

  const float fs1 = (float)(1.0 / (4194304.0 * 4096.0));
  const float fs2 = (float)(1.0 / (2097152.0 * 16384.0));
  const float fs3 = (float)(1.0 / (1048576.0 * 65536.0));

  init_slots<<<1, 64, 0, stream>>>(slots);
  l1_kernel<<<304, 256, 0, stream>>>(igt, iout, mask, slots);
  for (int l = 0; l < 6; ++l) {
    int elems = wpCout[l] * wpCin[l] * 9;
    pack_w<<<(elems + 255) / 256, 256, 0, stream>>>(w[l + 1], wpk + wpOff[l],
                                                    wpCin[l], wpCout[l]);
  }
  pack_w1<<<8, 256, 0, stream>>>(w[0], w1k);

  for (int n0 = 0; n0 < 2; n0 += NB) {
    for (int s = 0; s < 3; ++s) {
      pack2_kernel<<<NB * 1024, 256, 0, stream>>>(igt, iout, mask, Apk, s, n0, NB);
      conv1m<<<dim3(8, 64, NB), 256, 0, stream>>>(Apk, w1k, b[0], Y1);
      conv_f8p<<<dim3(8, 64, NB), 256, 0, stream>>>(
          Y1, wpk + wpOff[0], b[1], P1N8 + (size_t)s * NB * 4194304, P1Nb,
          64, 64, 512, 512);
      transpose_k<<<dim3(32, 32, NB * 2), 256, 0, stream>>>(
          P1Nb, (s ? pcT1 : pgT1), 64, 256, 256);
      if (s > 0) {
        perc_kernel<<<304, 256, 0, stream>>>(pgT1, pcT1, NB * 524288, slots);
        gram_mfma<128><<<dim3(4, 2, NB * 64), 256, 0, stream>>>(
            pgT1, pcT1, 256, 256, fs1, slots);
      }
    }
    conv_f8<<<dim3(4, 32, B3 * 2), 256, 0, stream>>>(
        P1N8, wpk + wpOff[1], b[2], T, 64, 128, 256, 256);
    conv_f8p<<<dim3(4, 32, B3 * 2), 256, 0, stream>>>(
        T, wpk + wpOff[2], b[3], P2N8, P2Nb, 128, 128, 256, 256);
    transpose_k<<<dim3(16, 16, B3 * 4), 256, 0, stream>>>(P2Nb, P2T, 128, 128, 128);
    for (int s = 1; s <= 2; ++s) {
      perc_kernel<<<304, 256, 0, stream>>>(
          P2T, P2T + (size_t)s * NB * 2097152, NB * 262144, slots);
      gram_mfma<128><<<dim3(2, 1, NB * 128), 256, 0, stream>>>(
          P2T, P2T + (size_t)s * NB * 2097152, 128, 128, fs2, slots);
    }
    conv_f8<<<dim3(2, 16, B3 * 4), 256, 0, stream>>>(
        P2N8, wpk + wpOff[3], b[4], Y5, 128, 256, 128, 128);
    conv_f8<<<dim3(2, 16, B3 * 4), 256, 0, stream>>>(
        Y5, wpk + wpOff[4], b[5], Y6, 256, 256, 128, 128);
    conv_f8p<<<dim3(2, 16, B3 * 4), 256, 0, stream>>>(
        Y6, wpk + wpOff[5], b[6], P3N8, P3Nb, 256, 256, 128, 128);
    transpose_k<<<dim3(8, 8, B3 * 8), 256, 0, stream>>>(P3Nb, P3T, 256, 64, 64);
    for (int s = 1; s <= 2; ++s) {
      perc_kernel<<<304, 256, 0, stream>>>(
          P3T, P3T + (size_t)s * NB * 1048576, NB * 131072, slots);
      gram_mfma<64><<<dim3(1, 1, NB * 256), 256, 0, stream>>>(
          P3T, P3T + (size_t)s * NB * 1048576, 64, 64, fs3, slots);
    }
  }

  combine_kernel<<<1, 64, 0, stream>>>(slots, (float*)d_out);
}

// Round 14
// 954.876 us; speedup vs baseline: 1.0696x; 1.0696x over previous
//
#include <hip/hip_runtime.h>
#include <hip/hip_bf16.h>

// ---------------------------------------------------------------------------
// VGG16 perceptual+style inpainting loss.  (r12 proven configuration)
// conv1: bf16 MFMA im2col-K32 -> fp8 (channel-permuted) output.
// conv2..7: fp8(e4m3) MFMA NHWC with K-PAIRED b128 LDS reads: activations
// stored with 64-channel groups permuted (pos = ((c>>3)&3)*16+((c>>5)&1)*8
// +(c&7)) so one ds_read_b128 feeds two K=32 MFMAs. A-fragments register-
// cached across dy. Pool epilogues dual-store fp8(perm) + bf16(logical).
// Gram: bf16 MFMA planar. l1/perc grid-stride.
// NOTE (r13 post-mortem): 16x16x32 + 16-lane-stride reads is the right shape;
// 32x32x16 with 32-lane-stride reads concentrates banks (2 groups) and
// regressed 953->1021. r12's SQ_LDS_BANK_CONFLICT = exactly 4x wave-b128
// reads = inherent phase accounting, not real conflicts.
// ---------------------------------------------------------------------------

typedef __attribute__((ext_vector_type(8))) short bf16x8_t;
typedef __attribute__((ext_vector_type(4))) float f32x4_t;

__device__ __forceinline__ float b2f(__hip_bfloat16 v) {
  return __bfloat162float(v);
}

__device__ __forceinline__ unsigned char f2fp8(float v) {
  return (unsigned char)(__builtin_amdgcn_cvt_pk_fp8_f32(v, v, 0, false) & 0xff);
}

__device__ __forceinline__ int p64(int c) {  // channel -> stored position
  return ((c >> 3) & 3) * 16 + ((c >> 5) & 1) * 8 + (c & 7);
}

__device__ __forceinline__ float blk_sum256(float v, float* s4) {
#pragma unroll
  for (int o = 32; o > 0; o >>= 1) v += __shfl_down(v, o);
  int w = threadIdx.x >> 6;
  if ((threadIdx.x & 63) == 0) s4[w] = v;
  __syncthreads();
  float r = s4[0] + s4[1] + s4[2] + s4[3];
  __syncthreads();
  return r;
}

__global__ void init_slots(float* slots) {
  if (threadIdx.x < 8) slots[threadIdx.x] = 0.0f;
}

__global__ __launch_bounds__(256) void l1_kernel(
    const float* __restrict__ igt, const float* __restrict__ iout,
    const float* __restrict__ mask, float* __restrict__ slots) {
  __shared__ float s4[4];
  float ah = 0.0f, av = 0.0f;
  for (int idx = blockIdx.x * 256 + threadIdx.x; idx < 1572864;
       idx += gridDim.x * 256) {
    int pix = idx & 262143;
    int n = idx / 786432;
    float mk = mask[n * 262144 + pix];
    bool m = (mk != 0.0f);
    float d = fabsf(iout[idx] - igt[idx]);
    if (m) av += d; else ah += d;
  }
  float r = blk_sum256(ah, s4);
  if (threadIdx.x == 0) atomicAdd(&slots[0], r);
  r = blk_sum256(av, s4);
  if (threadIdx.x == 0) atomicAdd(&slots[1], r);
}

// Pack fp32 OIHW weights -> fp8 [tap][cout][cin-permuted] (conv2..7).
__global__ __launch_bounds__(256) void pack_w(const float* __restrict__ w,
                                              unsigned char* __restrict__ wp,
                                              int Cin, int Cout) {
  int i = blockIdx.x * 256 + threadIdx.x;
  if (i >= Cout * Cin * 9) return;
  int o = i % 9;
  int rem = i / 9;
  int ci = rem % Cin;
  int co = rem / Cin;
  int cis = (ci & ~63) + p64(ci & 63);
  wp[((long)(o * Cout + co)) * Cin + cis] = f2fp8(w[i]);
}

// Pack conv1 weights [64][3][3][3] OIHW -> bf16 [co][32], k=dy*9+dx*3+ci.
__global__ __launch_bounds__(256) void pack_w1(const float* __restrict__ w,
                                               __hip_bfloat16* __restrict__ wk) {
  int i = blockIdx.x * 256 + threadIdx.x;
  if (i >= 64 * 32) return;
  int co = i >> 5, k = i & 31;
  float v = 0.0f;
  if (k < 27) {
    int dy = k / 9, r = k - dy * 9;
    int dx = r / 3, ci = r - dx * 3;
    v = w[((co * 3 + ci) * 3 + dy) * 3 + dx];
  }
  wk[i] = __float2bfloat16(v);
}

// Build im2col-K32 bf16 input Apk[nl][y][x][32] for stream sid. (r10-proven)
__global__ __launch_bounds__(256) void pack2_kernel(
    const float* __restrict__ igt, const float* __restrict__ iout,
    const float* __restrict__ mask, __hip_bfloat16* __restrict__ apk, int sid,
    int n0, int NB) {
  int idx = blockIdx.x * 256 + threadIdx.x;
  if (idx >= NB * 262144) return;
  int nl = idx >> 18;
  int pix = idx & 262143;
  int y = pix >> 9, x = pix & 511;
  int sample = n0 + nl;
  __align__(16) __hip_bfloat16 buf[32];
#pragma unroll
  for (int k = 27; k < 32; ++k) buf[k] = __float2bfloat16(0.0f);
  for (int dy = 0; dy < 3; ++dy)
    for (int dx = 0; dx < 3; ++dx) {
      int gy = y - 1 + dy, gx = x - 1 + dx;
      bool inb = (gy >= 0 && gy < 512 && gx >= 0 && gx < 512);
      int p = gy * 512 + gx;
      bool useG;
      if (sid == 0) useG = true;
      else if (sid == 1) useG = false;
      else useG = inb && (mask[sample * 262144 + (inb ? p : 0)] != 0.0f);
      const float* src = useG ? igt : iout;
#pragma unroll
      for (int ci = 0; ci < 3; ++ci) {
        float v = inb ? src[sample * 786432 + ci * 262144 + p] : 0.0f;
        buf[dy * 9 + dx * 3 + ci] = __float2bfloat16(v);
      }
    }
  __hip_bfloat16* dst = apk + (long)idx * 32;
#pragma unroll
  for (int q = 0; q < 4; ++q)
    *(uint4*)&dst[q * 8] = *(const uint4*)&buf[q * 8];
}

// conv1: K=32 bf16 MFMA GEMM -> fp8 NHWC Y1 (permuted channel positions).
__global__ __launch_bounds__(256, 2) void conv1m(
    const __hip_bfloat16* __restrict__ apk, const __hip_bfloat16* __restrict__ wk,
    const float* __restrict__ bias, unsigned char* __restrict__ out) {
  __shared__ __align__(16) short ApS[512 * 32];
  __shared__ __align__(16) short BwS[64 * 32];
  const int tid = threadIdx.x;
  const int lane = tid & 63;
  const int wv = tid >> 6;
  const int quad = lane >> 4, l15 = lane & 15;
  const int n = blockIdx.z;
  const int x0 = blockIdx.x << 6;
  const int y0 = blockIdx.y << 3;

  for (int e = tid; e < 2048; e += 256) {
    int q = e & 3, pos = e >> 2;
    int r = pos >> 6, c = pos & 63;
    *(uint4*)&ApS[pos * 32 + q * 8] =
        *(const uint4*)(apk + (((long)n * 512 + y0 + r) * 512 + x0 + c) * 32 +
                        q * 8);
  }
  if (tid < 256) {
    int q = tid & 3, co = tid >> 2;
    *(uint4*)&BwS[co * 32 + q * 8] = *(const uint4*)(wk + co * 32 + q * 8);
  }
  __syncthreads();

  f32x4_t acc[8][4];
#pragma unroll
  for (int mt = 0; mt < 8; ++mt)
#pragma unroll
    for (int nt = 0; nt < 4; ++nt) acc[mt][nt] = (f32x4_t)0.0f;

  bf16x8_t bf[4];
#pragma unroll
  for (int nt = 0; nt < 4; ++nt)
    bf[nt] = *(const bf16x8_t*)&BwS[(nt * 16 + l15) * 32 + quad * 8];
#pragma unroll
  for (int mt = 0; mt < 8; ++mt) {
    const int rl = 2 * wv + (mt >> 2);
    const int pl = (mt & 3) * 16 + l15;
    const bf16x8_t a = *(const bf16x8_t*)&ApS[(rl * 64 + pl) * 32 + quad * 8];
#pragma unroll
    for (int nt = 0; nt < 4; ++nt)
      acc[mt][nt] = __builtin_amdgcn_mfma_f32_16x16x32_bf16(a, bf[nt],
                                                            acc[mt][nt], 0, 0, 0);
  }

  float bv[4];
#pragma unroll
  for (int nt = 0; nt < 4; ++nt) bv[nt] = bias[nt * 16 + l15];
#pragma unroll
  for (int mt = 0; mt < 8; ++mt) {
    const int y = y0 + 2 * wv + (mt >> 2);
#pragma unroll
    for (int nt = 0; nt < 4; ++nt) {
      const int colp = p64(nt * 16 + l15);
#pragma unroll
      for (int reg = 0; reg < 4; ++reg) {
        int px = (mt & 3) * 16 + quad * 4 + reg;
        float v = fmaxf(acc[mt][nt][reg] + bv[nt], 0.0f);
        out[(((long)n * 512 + y) * 512 + x0 + px) * 64 + colp] = f2fp8(v);
      }
    }
  }
}

// ---------------------------------------------------------------------------
// conv_f8: fp8 MFMA 3x3 conv, K-paired b128 reads. Per-pixel LDS entry =
// 64B (one permuted 64-ch group): lane b128 at +quad*16 gives lo=k0..31
// fragment, hi=k32..63 fragment. A frags cached in regs across dy.
// Wave = 2 rows x 64 px x 64 co. LDS: A 42,240B + W 36,864B -> 2 blk/CU.
// ---------------------------------------------------------------------------
__global__ __launch_bounds__(256, 2) void conv_f8(
    const unsigned char* __restrict__ act, const unsigned char* __restrict__ wp,
    const float* __restrict__ bias, unsigned char* __restrict__ out, int Cin,
    int Cout, int H, int W) {
  __shared__ __align__(16) unsigned char ApS[660 * 64];
  __shared__ __align__(16) unsigned char BwS[576 * 64];
  const int tid = threadIdx.x;
  const int lane = tid & 63;
  const int wv = tid >> 6;
  const int quad = lane >> 4, l15 = lane & 15;
  const int coB = Cout >> 6;
  const int n = blockIdx.z / coB;
  const int co0 = (blockIdx.z % coB) << 6;
  const int x0 = blockIdx.x << 6;
  const int y0 = blockIdx.y << 3;

  f32x4_t acc[8][4];
#pragma unroll
  for (int mt = 0; mt < 8; ++mt)
#pragma unroll
    for (int nt = 0; nt < 4; ++nt) acc[mt][nt] = (f32x4_t)0.0f;

  for (int cb = 0; cb < Cin; cb += 64) {
    for (int e = tid; e < 2640; e += 256) {  // A: 660 px * 4 x 16B
      int q = e & 3, pos = e >> 2;
      int r = pos / 66, c = pos - r * 66;
      int gy = y0 - 1 + r, gx = x0 - 1 + c;
      uint4 v = make_uint4(0, 0, 0, 0);
      if (gy >= 0 && gy < H && gx >= 0 && gx < W)
        v = *(const uint4*)(act + ((long)((long)n * H + gy) * W + gx) * Cin +
                            cb + q * 16);
      *(uint4*)&ApS[pos * 64 + q * 16] = v;
    }
    for (int e = tid; e < 2304; e += 256) {  // W: 576 rows * 4 x 16B
      int q = e & 3, idx = e >> 2;
      int o = idx >> 6, co = idx & 63;
      *(uint4*)&BwS[idx * 64 + q * 16] =
          *(const uint4*)(wp + ((long)(o * Cout + co0 + co)) * Cin + cb +
                          q * 16);
    }
    __syncthreads();

#pragma unroll
    for (int dx = 0; dx < 3; ++dx) {
      uint4 F[4][4];
#pragma unroll
      for (int dr = 0; dr < 4; ++dr)
#pragma unroll
        for (int mc = 0; mc < 4; ++mc)
          F[dr][mc] = *(const uint4*)&ApS
              [((2 * wv + dr) * 66 + mc * 16 + l15 + dx) * 64 + quad * 16];
#pragma unroll
      for (int dy = 0; dy < 3; ++dy) {
        const int o = dy * 3 + dx;
        long long blo[4], bhi[4];
#pragma unroll
        for (int nt = 0; nt < 4; ++nt) {
          uint4 b4 = *(const uint4*)&BwS[((o << 6) + nt * 16 + l15) * 64 +
                                         quad * 16];
          blo[nt] = ((long long)b4.y << 32) | b4.x;
          bhi[nt] = ((long long)b4.w << 32) | b4.z;
        }
#pragma unroll
        for (int mt = 0; mt < 8; ++mt) {
          uint4 a4 = F[(mt >> 2) + dy][mt & 3];
          long long alo = ((long long)a4.y << 32) | a4.x;
          long long ahi = ((long long)a4.w << 32) | a4.z;
#pragma unroll
          for (int nt = 0; nt < 4; ++nt) {
            acc[mt][nt] = __builtin_amdgcn_mfma_f32_16x16x32_fp8_fp8(
                alo, blo[nt], acc[mt][nt], 0, 0, 0);
            acc[mt][nt] = __builtin_amdgcn_mfma_f32_16x16x32_fp8_fp8(
                ahi, bhi[nt], acc[mt][nt], 0, 0, 0);
          }
        }
      }
    }
    __syncthreads();
  }

  float bv[4];
#pragma unroll
  for (int nt = 0; nt < 4; ++nt) bv[nt] = bias[co0 + nt * 16 + l15];
#pragma unroll
  for (int mt = 0; mt < 8; ++mt) {
    const int y = y0 + 2 * wv + (mt >> 2);
#pragma unroll
    for (int nt = 0; nt < 4; ++nt) {
      const int colp = co0 + p64(nt * 16 + l15);
#pragma unroll
      for (int reg = 0; reg < 4; ++reg) {
        int px = (mt & 3) * 16 + quad * 4 + reg;
        float v = fmaxf(acc[mt][nt][reg] + bv[nt], 0.0f);
        out[(((long)n * H + y) * W + x0 + px) * Cout + colp] = f2fp8(v);
      }
    }
  }
}

// conv_f8p: conv_f8 + fused 2x2 maxpool; dual-store fp8(perm) + bf16(logical).
__global__ __launch_bounds__(256, 2) void conv_f8p(
    const unsigned char* __restrict__ act, const unsigned char* __restrict__ wp,
    const float* __restrict__ bias, unsigned char* __restrict__ outF,
    __hip_bfloat16* __restrict__ outB, int Cin, int Cout, int H, int W) {
  __shared__ __align__(16) unsigned char ApS[660 * 64];
  __shared__ __align__(16) unsigned char BwS[576 * 64];
  const int tid = threadIdx.x;
  const int lane = tid & 63;
  const int wv = tid >> 6;
  const int quad = lane >> 4, l15 = lane & 15;
  const int coB = Cout >> 6;
  const int n = blockIdx.z / coB;
  const int co0 = (blockIdx.z % coB) << 6;
  const int x0g = blockIdx.x << 6;
  const int y0 = blockIdx.y << 3;

  f32x4_t acc[8][4];
#pragma unroll
  for (int mt = 0; mt < 8; ++mt)
#pragma unroll
    for (int nt = 0; nt < 4; ++nt) acc[mt][nt] = (f32x4_t)0.0f;

  for (int cb = 0; cb < Cin; cb += 64) {
    for (int e = tid; e < 2640; e += 256) {
      int q = e & 3, pos = e >> 2;
      int r = pos / 66, c = pos - r * 66;
      int gy = y0 - 1 + r, gx = x0g - 1 + c;
      uint4 v = make_uint4(0, 0, 0, 0);
      if (gy >= 0 && gy < H && gx >= 0 && gx < W)
        v = *(const uint4*)(act + ((long)((long)n * H + gy) * W + gx) * Cin +
                            cb + q * 16);
      *(uint4*)&ApS[pos * 64 + q * 16] = v;
    }
    for (int e = tid; e < 2304; e += 256) {
      int q = e & 3, idx = e >> 2;
      int o = idx >> 6, co = idx & 63;
      *(uint4*)&BwS[idx * 64 + q * 16] =
          *(const uint4*)(wp + ((long)(o * Cout + co0 + co)) * Cin + cb +
                          q * 16);
    }
    __syncthreads();

#pragma unroll
    for (int dx = 0; dx < 3; ++dx) {
      uint4 F[4][4];
#pragma unroll
      for (int dr = 0; dr < 4; ++dr)
#pragma unroll
        for (int mc = 0; mc < 4; ++mc)
          F[dr][mc] = *(const uint4*)&ApS
              [((2 * wv + dr) * 66 + mc * 16 + l15 + dx) * 64 + quad * 16];
#pragma unroll
      for (int dy = 0; dy < 3; ++dy) {
        const int o = dy * 3 + dx;
        long long blo[4], bhi[4];
#pragma unroll
        for (int nt = 0; nt < 4; ++nt) {
          uint4 b4 = *(const uint4*)&BwS[((o << 6) + nt * 16 + l15) * 64 +
                                         quad * 16];
          blo[nt] = ((long long)b4.y << 32) | b4.x;
          bhi[nt] = ((long long)b4.w << 32) | b4.z;
        }
#pragma unroll
        for (int mt = 0; mt < 8; ++mt) {
          uint4 a4 = F[(mt >> 2) + dy][mt & 3];
          long long alo = ((long long)a4.y << 32) | a4.x;
          long long ahi = ((long long)a4.w << 32) | a4.z;
#pragma unroll
          for (int nt = 0; nt < 4; ++nt) {
            acc[mt][nt] = __builtin_amdgcn_mfma_f32_16x16x32_fp8_fp8(
                alo, blo[nt], acc[mt][nt], 0, 0, 0);
            acc[mt][nt] = __builtin_amdgcn_mfma_f32_16x16x32_fp8_fp8(
                ahi, bhi[nt], acc[mt][nt], 0, 0, 0);
          }
        }
      }
    }
    __syncthreads();
  }

  const int Ho = H >> 1, Wo = W >> 1;
  const int ho = (blockIdx.y << 2) + wv;
  float bv[4];
#pragma unroll
  for (int nt = 0; nt < 4; ++nt) bv[nt] = bias[co0 + nt * 16 + l15];
#pragma unroll
  for (int mtA = 0; mtA < 4; ++mtA)
#pragma unroll
    for (int nt = 0; nt < 4; ++nt) {
      const int col = co0 + nt * 16 + l15;
      const int colp = co0 + p64(nt * 16 + l15);
#pragma unroll
      for (int half = 0; half < 2; ++half) {
        float m0 = fmaxf(
            fmaxf(acc[mtA][nt][2 * half], acc[mtA][nt][2 * half + 1]),
            fmaxf(acc[mtA + 4][nt][2 * half], acc[mtA + 4][nt][2 * half + 1]));
        float v = fmaxf(m0 + bv[nt], 0.0f);
        int wo = (blockIdx.x << 5) + mtA * 8 + quad * 2 + half;
        long rowbase = (((long)n * Ho + ho) * Wo + wo) * Cout;
        outF[rowbase + colp] = f2fp8(v);
        outB[rowbase + col] = __float2bfloat16(v);
      }
    }
}

// NHWC [j][Ho][Wo][C] -> col-major planar [(j*C+c)][Wo][Ho]. (r10-proven)
__global__ __launch_bounds__(256) void transpose_k(
    const __hip_bfloat16* __restrict__ in, __hip_bfloat16* __restrict__ out,
    int C, int Ho, int Wo) {
  const int cl = threadIdx.x & 31;
  const int wl = threadIdx.x >> 5;
  const int cg = C >> 5;
  const int j = blockIdx.z / cg;
  const int c = (blockIdx.z % cg) * 32 + cl;
  const int wo = blockIdx.x * 8 + wl;
  const int ho0 = blockIdx.y * 8;
  __align__(16) __hip_bfloat16 res[8];
#pragma unroll
  for (int i = 0; i < 8; ++i)
    res[i] = in[(((long)j * Ho + ho0 + i) * Wo + wo) * C + c];
  *(uint4*)&out[((long)(j * C + c) * Wo + wo) * Ho + ho0] =
      *(const uint4*)res;
}

// l_perc partial: sum |cur - gt| over 8*M8 bf16 elements -> slots[2]
__global__ __launch_bounds__(256) void perc_kernel(
    const __hip_bfloat16* __restrict__ gt, const __hip_bfloat16* __restrict__ cur,
    int M8, float* __restrict__ slots) {
  __shared__ float s4[4];
  const uint4* g4 = (const uint4*)gt;
  const uint4* c4 = (const uint4*)cur;
  float acc = 0.0f;
  for (int i = blockIdx.x * 256 + threadIdx.x; i < M8; i += gridDim.x * 256) {
    uint4 g = g4[i], c = c4[i];
    const unsigned* gu = (const unsigned*)&g;
    const unsigned* cu = (const unsigned*)&c;
#pragma unroll
    for (int k = 0; k < 4; ++k) {
      float g0 = __uint_as_float(gu[k] << 16);
      float g1 = __uint_as_float(gu[k] & 0xffff0000u);
      float c0 = __uint_as_float(cu[k] << 16);
      float c1 = __uint_as_float(cu[k] & 0xffff0000u);
      acc += fabsf(c0 - g0) + fabsf(c1 - g1);
    }
  }
  float r = blk_sum256(acc, s4);
  if (threadIdx.x == 0) atomicAdd(&slots[2], r);
}

// Style partial via bf16 MFMA (r5-proven). Inputs col-major planar bf16.
template <int BM>
__global__ __launch_bounds__(256) void gram_mfma(
    const __hip_bfloat16* __restrict__ gt_p,
    const __hip_bfloat16* __restrict__ cur_p, int Wp, int Hp, float fscale,
    float* __restrict__ slots) {
  constexpr int COLS = BM + 64;
  constexpr int WR = BM / 4;
  constexpr int MT = WR / 16;
  __shared__ __align__(16) short S[2 * COLS * 40];
  __shared__ float s4[4];
  const int tid = threadIdx.x;
  const int lane = tid & 63;
  const int wvi = tid >> 6;
  const int quad = lane >> 4, l15 = lane & 15;
  const int vt = blockIdx.x * 64;
  const int wt = blockIdx.y * BM;
  const long plane = (long)blockIdx.z * Wp * Hp;
  const __hip_bfloat16* bases[2] = {gt_p + plane, cur_p + plane};

  f32x4_t acc[2][MT][4];
#pragma unroll
  for (int t = 0; t < 2; ++t)
#pragma unroll
    for (int mt = 0; mt < MT; ++mt)
#pragma unroll
      for (int nt = 0; nt < 4; ++nt) acc[t][mt][nt] = (f32x4_t)0.0f;

  const int nchunk = 2 * COLS * 4;
  for (int h0 = 0; h0 < Hp; h0 += 32) {
    for (int e = tid; e < nchunk; e += 256) {
      int chunk = e & 3;
      int colt = e >> 2;
      int t = colt / COLS;
      int col = colt - t * COLS;
      int sc = (col < BM) ? (wt + col) : (vt + col - BM);
      uint4 v = *(const uint4*)(bases[t] + (long)sc * Hp + h0 + chunk * 8);
      *(uint4*)&S[(t * COLS + col) * 40 + chunk * 8] = v;
    }
    __syncthreads();
#pragma unroll
    for (int t = 0; t < 2; ++t) {
      bf16x8_t bf[4];
#pragma unroll
      for (int nt = 0; nt < 4; ++nt)
        bf[nt] = *(const bf16x8_t*)&S[(t * COLS + BM + nt * 16 + l15) * 40 +
                                      quad * 8];
#pragma unroll
      for (int mt = 0; mt < MT; ++mt) {
        bf16x8_t a = *(const bf16x8_t*)&S[(t * COLS + wvi * WR + mt * 16 + l15) *
                                              40 + quad * 8];
#pragma unroll
        for (int nt = 0; nt < 4; ++nt)
          acc[t][mt][nt] = __builtin_amdgcn_mfma_f32_16x16x32_bf16(
              a, bf[nt], acc[t][mt][nt], 0, 0, 0);
      }
    }
    __syncthreads();
  }

  float local = 0.0f;
#pragma unroll
  for (int mt = 0; mt < MT; ++mt)
#pragma unroll
    for (int nt = 0; nt < 4; ++nt)
#pragma unroll
      for (int reg = 0; reg < 4; ++reg)
        local += fabsf(acc[1][mt][nt][reg] - acc[0][mt][nt][reg]);
  float r = blk_sum256(local, s4);
  if (tid == 0) atomicAdd(&slots[3], r * fscale);
}

__global__ void combine_kernel(const float* __restrict__ slots,
                               float* __restrict__ out) {
  if (threadIdx.x == 0) {
    const float Nn = 1572864.0f;
    const float Nigt = 8388608.0f;
    out[0] = 2.0f * slots[0] / Nn + slots[1] / Nn + slots[2] / Nigt + slots[3];
  }
}

extern "C" void kernel_launch(void* const* d_in, const int* in_sizes, int n_in,
                              void* d_out, int out_size, void* d_ws,
                              size_t ws_size, hipStream_t stream) {
  (void)in_sizes; (void)n_in; (void)out_size;
  const float* igt = (const float*)d_in[0];
  const float* iout = (const float*)d_in[1];
  const float* mask = (const float*)d_in[2];
  const float* w[7];
  const float* b[7];
  for (int i = 0; i < 7; ++i) {
    w[i] = (const float*)d_in[3 + 2 * i];
    b[i] = (const float*)d_in[4 + 2 * i];
  }
  float* slots = (float*)d_ws;

  unsigned char* wpk = (unsigned char*)((char*)d_ws + 256);
  const long wpOff[6] = {0, 36864, 110592, 258048, 552960, 1142784};
  const int wpCin[6] = {64, 64, 128, 128, 256, 256};
  const int wpCout[6] = {64, 128, 128, 256, 256, 256};
  __hip_bfloat16* w1k = (__hip_bfloat16*)((char*)d_ws + 256 + 1732608);
  // weights end at byte 1,736,960

  const size_t NEED2 = 194674944ULL;
  const int NB = (ws_size >= NEED2) ? 2 : 1;
  const int B3 = 3 * NB;

  char* base = (char*)d_ws + 1736960;
  __hip_bfloat16* Apk = (__hip_bfloat16*)base;
  unsigned char* Y1 = (unsigned char*)(base + (size_t)NB * 16777216);
  unsigned char* P1N8 = (unsigned char*)(base + (size_t)NB * 33554432);
  __hip_bfloat16* P1Nb = (__hip_bfloat16*)(base + (size_t)NB * 46137344);
  __hip_bfloat16* pgT1 = (__hip_bfloat16*)(base + (size_t)NB * 54525952);
  __hip_bfloat16* pcT1 = (__hip_bfloat16*)(base + (size_t)NB * 62914560);
  __hip_bfloat16* P2Nb = (__hip_bfloat16*)(base + (size_t)NB * 71303168);
  __hip_bfloat16* P2T = (__hip_bfloat16*)(base + (size_t)NB * 83886080);
  unsigned char* T = (unsigned char*)base;
  unsigned char* P2N8 = (unsigned char*)(base + (size_t)NB * 46137344);
  unsigned char* Y5 = (unsigned char*)base;
  unsigned char* Y6 = (unsigned char*)(base + (size_t)NB * 12582912);
  __hip_bfloat16* P3Nb = (__hip_bfloat16*)(base + (size_t)NB * 33554432);
  __hip_bfloat16* P3T = (__hip_bfloat16*)(base + (size_t)NB * 39845888);
  unsigned char* P3N8 = (unsigned char*)(base + (size_t)NB * 46137344);

  const float fs1 = (float)(1.0 / (4194304.0 * 4096.0));
  const float fs2 = (float)(1.0 / (2097152.0 * 16384.0));
  const float fs3 = (float)(1.0 / (1048576.0 * 65536.0));

  init_slots<<<1, 64, 0, stream>>>(slots);
  l1_kernel<<<304, 256, 0, stream>>>(igt, iout, mask, slots);
  for (int l = 0; l < 6; ++l) {
    int elems = wpCout[l] * wpCin[l] * 9;
    pack_w<<<(elems + 255) / 256, 256, 0, stream>>>(w[l + 1], wpk + wpOff[l],
                                                    wpCin[l], wpCout[l]);
  }
  pack_w1<<<8, 256, 0, stream>>>(w[0], w1k);

  for (int n0 = 0; n0 < 2; n0 += NB) {
    for (int s = 0; s < 3; ++s) {
      pack2_kernel<<<NB * 1024, 256, 0, stream>>>(igt, iout, mask, Apk, s, n0, NB);
      conv1m<<<dim3(8, 64, NB), 256, 0, stream>>>(Apk, w1k, b[0], Y1);
      conv_f8p<<<dim3(8, 64, NB), 256, 0, stream>>>(
          Y1, wpk + wpOff[0], b[1], P1N8 + (size_t)s * NB * 4194304, P1Nb,
          64, 64, 512, 512);
      transpose_k<<<dim3(32, 32, NB * 2), 256, 0, stream>>>(
          P1Nb, (s ? pcT1 : pgT1), 64, 256, 256);
      if (s > 0) {
        perc_kernel<<<304, 256, 0, stream>>>(pgT1, pcT1, NB * 524288, slots);
        gram_mfma<128><<<dim3(4, 2, NB * 64), 256, 0, stream>>>(
            pgT1, pcT1, 256, 256, fs1, slots);
      }
    }
    conv_f8<<<dim3(4, 32, B3 * 2), 256, 0, stream>>>(
        P1N8, wpk + wpOff[1], b[2], T, 64, 128, 256, 256);
    conv_f8p<<<dim3(4, 32, B3 * 2), 256, 0, stream>>>(
        T, wpk + wpOff[2], b[3], P2N8, P2Nb, 128, 128, 256, 256);
    transpose_k<<<dim3(16, 16, B3 * 4), 256, 0, stream>>>(P2Nb, P2T, 128, 128, 128);
    for (int s = 1; s <= 2; ++s) {
      perc_kernel<<<304, 256, 0, stream>>>(
          P2T, P2T + (size_t)s * NB * 2097152, NB * 262144, slots);
      gram_mfma<128><<<dim3(2, 1, NB * 128), 256, 0, stream>>>(
          P2T, P2T + (size_t)s * NB * 2097152, 128, 128, fs2, slots);
    }
    conv_f8<<<dim3(2, 16, B3 * 4), 256, 0, stream>>>(
        P2N8, wpk + wpOff[3], b[4], Y5, 128, 256, 128, 128);
    conv_f8<<<dim3(2, 16, B3 * 4), 256, 0, stream>>>(
        Y5, wpk + wpOff[4], b[5], Y6, 256, 256, 128, 128);
    conv_f8p<<<dim3(2, 16, B3 * 4), 256, 0, stream>>>(
        Y6, wpk + wpOff[5], b[6], P3N8, P3Nb, 256, 256, 128, 128);
    transpose_k<<<dim3(8, 8, B3 * 8), 256, 0, stream>>>(P3Nb, P3T, 256, 64, 64);
    for (int s = 1; s <= 2; ++s) {
      perc_kernel<<<304, 256, 0, stream>>>(
          P3T, P3T + (size_t)s * NB * 1048576, NB * 131072, slots);
      gram_mfma<64><<<dim3(1, 1, NB * 256), 256, 0, stream>>>(
          P3T, P3T + (size_t)s * NB * 1048576, 64, 64, fs3, slots);
    }
  }

  combine_kernel<<<1, 64, 0, stream>>>(slots, (float*)d_out);
}